// Round 7
// baseline (353.236 us; speedup 1.0000x reference)
//
#include <hip/hip_runtime.h>

// FavorAttention (Performer FAVOR+) — B=4,H=8,D=64,N=8192,M=256, fp32 in/out.
// R8: latency attack on both big kernels.
// kv: back to 256-thread geometry (R7's 512-thr did not help: all blocks
// co-resident, per-block serial chain is the time) + T14 register prefetch:
// chunk ch+1's global loads issue right after ch's LDS writes and complete
// under ch's GEMM/exp compute. KSTAB const stabilizer kept (R7 math, passed).
// out: q-side stabilizer removed from the critical path. Algebra:
// out = (A' + g*S_d)/(B' + g*T), A'/B' computed with NO working stabilizer
// (exp arg = u*DNRM - dq, <= e^14, fp32/bf16 safe), g = eps*exp(stab_n) with
// stab_n = true per-token max tracked as a free fmax and consumed after PV.
// S_d = Sum_m kv[m][d], T = Sum_m key_norm[m]: accumulated in kvred (atomics,
// 8 KB memset). Deletes cw/stabl cross-wave reduce + 2 barriers between GEMM
// and exp; dql compute overlaps GEMM_uq; knl preloaded to regs (kills 48
// scalar LDS reads in the serial exp phase).

typedef short s16x8 __attribute__((ext_vector_type(8)));
typedef float f32x4 __attribute__((ext_vector_type(4)));

#define Dv 64
#define Nv 8192
#define Mv 256
#define BHv 32
#define SPL 16
#define NSPL (Nv / SPL)   // 512
#define NCH (NSPL / 64)   // 8

#define DNRM 0.3535533905932738f   // 64^-0.25
#define EPSV 1e-6f
#define KSTAB 15.0f                // constant k-side working stabilizer

// ws layout (float offsets)
#define OFF_SD 0                                // [32][64] Sum_m kv (atomic)
#define OFF_T (OFF_SD + BHv * Dv)               // [32] Sum_m key_norm (atomic)
#define OFF_SGM (OFF_T + BHv)                   // [32][16][4] per-(split,wave) sigma
#define OFF_SVP (OFF_SGM + BHv * SPL * 4)       // [32][16][64] V col-sum partials
#define OFF_KNP (OFF_SVP + BHv * SPL * 64)      // [32][16][256]
#define OFF_KNF (OFF_KNP + BHv * SPL * Mv)      // [32][256]
#define OFF_KVP (OFF_KNF + BHv * Mv)            // [32][16][256][64] fp32
#define OFF_KVT (OFF_KVP + BHv * SPL * Mv * Dv) // [32][64][256] bf16
#define ZERO_FLOATS (OFF_SGM)                   // memset SD+T region

__device__ __forceinline__ unsigned short f2b(float x) {
    return __builtin_bit_cast(unsigned short, (__bf16)x);
}

__device__ __forceinline__ s16x8 load_pfrag(const float* __restrict__ proj, int m,
                                            int kc, int q) {
    const float* p = proj + m * 64 + kc * 32 + q * 8;
    s16x8 r;
#pragma unroll
    for (int j = 0; j < 8; ++j) r[j] = (short)f2b(p[j]);
    return r;
}

// ---------------------------------------------------------------------------
// kv: 256 threads. Per chunk: write staged regs -> LDS, ISSUE next chunk's
// loads (they land under this chunk's compute), then GEMM1 -> exp -> GEMM2.
__global__ __launch_bounds__(256, 2) void favor_kv(const float* __restrict__ key,
                                                   const float* __restrict__ value,
                                                   const float* __restrict__ proj,
                                                   float* __restrict__ ws) {
    __shared__ __align__(16) unsigned short KT[64][72];   // [n][d]
    __shared__ __align__(16) unsigned short VL[64][72];   // [d][n]
    __shared__ __align__(16) unsigned short PH[256][40];  // [m][32n half] phi
    __shared__ __align__(16) float dred[16][64];          // diag partials [g][n]
    __shared__ __align__(16) float dgl[64];               // diag_k + KSTAB
    const int tid = threadIdx.x;
    const int w = tid >> 6, l = tid & 63, c = l & 15, q = l >> 4;
    const int g = tid >> 4, cs = tid & 15;
    const int s = blockIdx.x, bh = blockIdx.y;
    const float* kp = key + (size_t)bh * Dv * Nv;
    const float* vp = value + (size_t)bh * Dv * Nv;

    s16x8 P[4][2];
#pragma unroll
    for (int mt = 0; mt < 4; ++mt)
#pragma unroll
        for (int kc = 0; kc < 2; ++kc)
            P[mt][kc] = load_pfrag(proj, (4 * w + mt) * 16 + c, kc, q);

    f32x4 kva[4][4];
#pragma unroll
    for (int mt = 0; mt < 4; ++mt)
#pragma unroll
        for (int dt = 0; dt < 4; ++dt) kva[mt][dt] = (f32x4){0.f, 0.f, 0.f, 0.f};
    float kn[4] = {0.f, 0.f, 0.f, 0.f};
    float sv[4] = {0.f, 0.f, 0.f, 0.f};
    float tmax = -3.0e38f;

    // prologue: load chunk 0 into regs
    float4 kk[4], vv[4];
    {
        const int n0 = s * NSPL;
#pragma unroll
        for (int di = 0; di < 4; ++di) {
            kk[di] = *(const float4*)&kp[(4 * g + di) * Nv + n0 + 4 * cs];
            vv[di] = *(const float4*)&vp[(4 * g + di) * Nv + n0 + 4 * cs];
        }
    }

    for (int ch = 0; ch < NCH; ++ch) {
        if (ch) __syncthreads();
        // stage current chunk from regs
#pragma unroll
        for (int j = 0; j < 4; ++j) {
            const float k0 = ((const float*)&kk[0])[j];
            const float k1 = ((const float*)&kk[1])[j];
            const float k2 = ((const float*)&kk[2])[j];
            const float k3 = ((const float*)&kk[3])[j];
            *(short4*)&KT[4 * cs + j][4 * g] =
                make_short4((short)f2b(k0), (short)f2b(k1), (short)f2b(k2),
                            (short)f2b(k3));
            dred[g][4 * cs + j] = (k0 * k0 + k1 * k1) + (k2 * k2 + k3 * k3);
        }
#pragma unroll
        for (int di = 0; di < 4; ++di) {
            *(short4*)&VL[4 * g + di][4 * cs] = make_short4(
                (short)f2b(vv[di].x), (short)f2b(vv[di].y),
                (short)f2b(vv[di].z), (short)f2b(vv[di].w));
            sv[di] += (vv[di].x + vv[di].y) + (vv[di].z + vv[di].w);
        }
        // T14: issue next chunk's loads now; they complete under compute below
        if (ch + 1 < NCH) {
            const int n1 = s * NSPL + (ch + 1) * 64;
#pragma unroll
            for (int di = 0; di < 4; ++di) {
                kk[di] = *(const float4*)&kp[(4 * g + di) * Nv + n1 + 4 * cs];
                vv[di] = *(const float4*)&vp[(4 * g + di) * Nv + n1 + 4 * cs];
            }
        }
        __syncthreads();
        if (tid < 64) {
            float ds = 0.f;
#pragma unroll
            for (int gg = 0; gg < 16; ++gg) ds += dred[gg][tid];
            dgl[tid] = ds * 0.0625f + KSTAB;  // exp arg = u*DNRM - dgl
        }
        __syncthreads();
#pragma unroll
        for (int h = 0; h < 2; ++h) {
#pragma unroll
            for (int nt2 = 0; nt2 < 2; ++nt2) {
                const int nt = 2 * h + nt2;
                const s16x8 a0 = *(const s16x8*)&KT[nt * 16 + c][q * 8];
                const s16x8 a1 = *(const s16x8*)&KT[nt * 16 + c][32 + q * 8];
                const float4 dg = *(const float4*)&dgl[nt * 16 + q * 4];
#pragma unroll
                for (int mt = 0; mt < 4; ++mt) {
                    f32x4 u = {0.f, 0.f, 0.f, 0.f};
                    u = __builtin_amdgcn_mfma_f32_16x16x32_bf16(a0, P[mt][0], u, 0, 0, 0);
                    u = __builtin_amdgcn_mfma_f32_16x16x32_bf16(a1, P[mt][1], u, 0, 0, 0);
                    tmax = fmaxf(tmax, fmaxf(fmaxf(u[0], u[1]), fmaxf(u[2], u[3])));
                    const float e0 = __expf(__builtin_fmaf(u[0], DNRM, -dg.x));
                    const float e1 = __expf(__builtin_fmaf(u[1], DNRM, -dg.y));
                    const float e2 = __expf(__builtin_fmaf(u[2], DNRM, -dg.z));
                    const float e3 = __expf(__builtin_fmaf(u[3], DNRM, -dg.w));
                    kn[mt] += (e0 + e1) + (e2 + e3);
                    *(short4*)&PH[(4 * w + mt) * 16 + c][nt2 * 16 + q * 4] =
                        make_short4((short)f2b(e0), (short)f2b(e1),
                                    (short)f2b(e2), (short)f2b(e3));
                }
            }
            s16x8 bf[4];
#pragma unroll
            for (int dt = 0; dt < 4; ++dt)
                bf[dt] = *(const s16x8*)&VL[dt * 16 + c][h * 32 + q * 8];
#pragma unroll
            for (int mt = 0; mt < 4; ++mt) {
                const s16x8 a = *(const s16x8*)&PH[(4 * w + mt) * 16 + c][q * 8];
#pragma unroll
                for (int dt = 0; dt < 4; ++dt)
                    kva[mt][dt] = __builtin_amdgcn_mfma_f32_16x16x32_bf16(
                        a, bf[dt], kva[mt][dt], 0, 0, 0);
            }
        }
    }
    // sigma = true per-wave raw max * DNRM (one reduce per kernel)
#pragma unroll
    for (int off = 1; off < 64; off <<= 1)
        tmax = fmaxf(tmax, __shfl_xor(tmax, off, 64));
    if (l == 0) ws[OFF_SGM + (bh * SPL + s) * 4 + w] = tmax * DNRM;
    float* kvp = ws + OFF_KVP + (size_t)(bh * SPL + s) * Mv * Dv;
#pragma unroll
    for (int mt = 0; mt < 4; ++mt) {
        const int mrow = (4 * w + mt) * 16 + 4 * q;
#pragma unroll
        for (int dt = 0; dt < 4; ++dt) {
            const int dcol = dt * 16 + c;
#pragma unroll
            for (int r = 0; r < 4; ++r)
                kvp[(size_t)(mrow + r) * Dv + dcol] = kva[mt][dt][r];
        }
    }
#pragma unroll
    for (int mt = 0; mt < 4; ++mt) {
        kn[mt] += __shfl_xor(kn[mt], 16, 64);
        kn[mt] += __shfl_xor(kn[mt], 32, 64);
    }
    if (q == 0) {
        float* knp = ws + OFF_KNP + (bh * SPL + s) * Mv;
#pragma unroll
        for (int mt = 0; mt < 4; ++mt) knp[(4 * w + mt) * 16 + c] = kn[mt];
    }
    // V col-sum reduce (reuse dred region; its readers finished pre-barrier)
    __syncthreads();
    float* sp = &dred[0][0];  // as [64][16]
#pragma unroll
    for (int di = 0; di < 4; ++di) sp[(4 * g + di) * 16 + cs] = sv[di];
    __syncthreads();
    if (tid < 64) {
        float t2 = 0.f;
#pragma unroll
        for (int j = 0; j < 16; ++j) t2 += sp[tid * 16 + j];
        ws[OFF_SVP + (bh * SPL + s) * 64 + tid] = t2;
    }
}

// ---------------------------------------------------------------------------
// reduce split partials, uniform alpha = exp(KSTAB - G); add eps terms.
// Also accumulates S_d = Sum_m kv[m][d] and T = Sum_m key_norm[m] (atomics).
__global__ __launch_bounds__(256) void favor_kvred(float* __restrict__ ws) {
    __shared__ float sAl;
    __shared__ float svl[64];
    const int t = threadIdx.x, f = blockIdx.x, bh = blockIdx.y;
    const int flat = f * 1024 + t * 4;
    const int m = flat >> 6, d0 = flat & 63;
    if (t < 64) {
        float v = ws[OFF_SGM + bh * 64 + t];
#pragma unroll
        for (int off = 1; off < 64; off <<= 1)
            v = fmaxf(v, __shfl_xor(v, off, 64));
        if (t == 0) sAl = __expf(KSTAB - v);
    } else if (t < 128) {
        const int d = t - 64;
        float x = 0.f;
#pragma unroll
        for (int s2 = 0; s2 < SPL; ++s2)
            x += ws[OFF_SVP + (bh * SPL + s2) * 64 + d];
        svl[d] = x;
    }
    __syncthreads();
    const float al = sAl;
    float4 acc = make_float4(0.f, 0.f, 0.f, 0.f);
    for (int s2 = 0; s2 < SPL; ++s2) {
        const float4 v =
            *(const float4*)&ws[OFF_KVP + ((size_t)(bh * SPL + s2) << 14) + flat];
        acc.x += v.x; acc.y += v.y; acc.z += v.z; acc.w += v.w;
    }
    acc.x = acc.x * al + EPSV * svl[d0 + 0];
    acc.y = acc.y * al + EPSV * svl[d0 + 1];
    acc.z = acc.z * al + EPSV * svl[d0 + 2];
    acc.w = acc.w * al + EPSV * svl[d0 + 3];
    unsigned short* kvT = (unsigned short*)(ws + OFF_KVT);
    kvT[(bh * 64 + d0 + 0) * 256 + m] = f2b(acc.x);
    kvT[(bh * 64 + d0 + 1) * 256 + m] = f2b(acc.y);
    kvT[(bh * 64 + d0 + 2) * 256 + m] = f2b(acc.z);
    kvT[(bh * 64 + d0 + 3) * 256 + m] = f2b(acc.w);
    atomicAdd(&ws[OFF_SD + bh * 64 + d0 + 0], acc.x);
    atomicAdd(&ws[OFF_SD + bh * 64 + d0 + 1], acc.y);
    atomicAdd(&ws[OFF_SD + bh * 64 + d0 + 2], acc.z);
    atomicAdd(&ws[OFF_SD + bh * 64 + d0 + 3], acc.w);
    if (t < 16) {
        const int mm = f * 16 + t;
        float kk = 0.f;
        for (int s2 = 0; s2 < SPL; ++s2)
            kk += ws[OFF_KNP + (bh * SPL + s2) * Mv + mm];
        const float knf = kk * al + EPSV * (float)Nv;
        ws[OFF_KNF + bh * Mv + mm] = knf;
        atomicAdd(&ws[OFF_T + bh], knf);
    }
}

// ---------------------------------------------------------------------------
// out: stage Q (+diag_q) -> [dql overlaps GEMM_uq] -> exp with NO stabilizer
// (tracks per-token raw max for free) -> PHT + np -> PV -> normalize with
// gamma = eps*exp(stab_n): out = (acc + gamma*S_d) / (np + gamma*T).
__global__ __launch_bounds__(256, 2) void favor_out(const float* __restrict__ query,
                                                    const float* __restrict__ proj,
                                                    const float* __restrict__ ws,
                                                    float* __restrict__ out) {
    __shared__ __align__(16) unsigned short PHT[64][264];  // [n][m] phi^T (aliased)
    __shared__ float npart[4][64];  // per-wave denominator partials
    __shared__ float knl[256];
    __shared__ float cw[4][64];     // per-wave col-max (raw u)
    __shared__ float dql[64];
    __shared__ float Sl[64];
    __shared__ float Ts;
    // aliases inside PHT region (dead before first PHT write):
    unsigned short (*QT)[72] = (unsigned short (*)[72]) & PHT[0][0];  // 9216 B
    float (*dred)[64] = (float (*)[64])((char*)&PHT[0][0] + 9216);    // 4096 B
    const int tid = threadIdx.x;
    const int w = tid >> 6, l = tid & 63, c = l & 15, q = l >> 4;
    const int g = tid >> 4, cs = tid & 15;
    const int nb = blockIdx.x, bh = blockIdx.y;
    const int n0 = nb * 64;
    const float* qp = query + (size_t)bh * Dv * Nv;
    const unsigned short* kvT =
        (const unsigned short*)(ws + OFF_KVT) + (size_t)bh * 64 * 256;

    // stage Q transposed (b64 writes) + diag_q partials
    {
        float4 qq[4];
#pragma unroll
        for (int di = 0; di < 4; ++di)
            qq[di] = *(const float4*)&qp[(4 * g + di) * Nv + n0 + 4 * cs];
#pragma unroll
        for (int j = 0; j < 4; ++j) {
            const float v0 = ((const float*)&qq[0])[j];
            const float v1 = ((const float*)&qq[1])[j];
            const float v2 = ((const float*)&qq[2])[j];
            const float v3 = ((const float*)&qq[3])[j];
            *(short4*)&QT[4 * cs + j][4 * g] =
                make_short4((short)f2b(v0), (short)f2b(v1), (short)f2b(v2),
                            (short)f2b(v3));
            dred[g][4 * cs + j] = (v0 * v0 + v1 * v1) + (v2 * v2 + v3 * v3);
        }
    }
    knl[tid] = ws[OFF_KNF + bh * Mv + tid];
    if (tid < 64) Sl[tid] = ws[OFF_SD + bh * 64 + tid];
    if (tid == 0) Ts = ws[OFF_T + bh];

    s16x8 P[4][2];
#pragma unroll
    for (int mt = 0; mt < 4; ++mt)
#pragma unroll
        for (int kc = 0; kc < 2; ++kc)
            P[mt][kc] = load_pfrag(proj, (4 * w + mt) * 16 + c, kc, q);
    __syncthreads();

    // dql compute (tid<64) overlaps GEMM_uq on the other threads
    if (tid < 64) {
        float dsum = 0.f;
#pragma unroll
        for (int gg = 0; gg < 16; ++gg) dsum += dred[gg][tid];
        dql[tid] = dsum * 0.0625f;
    }
    // preload this thread's 16 knl values (nt-invariant: mb = (4w+mt)*16+4q)
    float knr[4][4];
#pragma unroll
    for (int mt = 0; mt < 4; ++mt) {
        const int mb = (4 * w + mt) * 16 + 4 * q;
#pragma unroll
        for (int r = 0; r < 4; ++r) knr[mt][r] = knl[mb + r];
    }

    // GEMM_uq: D[m][n], wave w owns m = 64w..64w+63
    f32x4 u[4][4];
#pragma unroll
    for (int mt = 0; mt < 4; ++mt)
#pragma unroll
        for (int nt = 0; nt < 4; ++nt) u[mt][nt] = (f32x4){0.f, 0.f, 0.f, 0.f};
#pragma unroll
    for (int nt = 0; nt < 4; ++nt) {
        const s16x8 b0 = *(const s16x8*)&QT[nt * 16 + c][q * 8];
        const s16x8 b1 = *(const s16x8*)&QT[nt * 16 + c][32 + q * 8];
#pragma unroll
        for (int mt = 0; mt < 4; ++mt) {
            u[mt][nt] =
                __builtin_amdgcn_mfma_f32_16x16x32_bf16(P[mt][0], b0, u[mt][nt], 0, 0, 0);
            u[mt][nt] =
                __builtin_amdgcn_mfma_f32_16x16x32_bf16(P[mt][1], b1, u[mt][nt], 0, 0, 0);
        }
    }
    __syncthreads();  // dql ready; QT/dred reads done -> PHT writes safe
    // exp (no stabilizer) -> PHT + np partials + free col-max tracking
#pragma unroll
    for (int nt = 0; nt < 4; ++nt) {
        const float dq = dql[nt * 16 + c];
        float np = 0.f;
        float vm = -3.4e38f;
#pragma unroll
        for (int mt = 0; mt < 4; ++mt) {
            vm = fmaxf(vm, fmaxf(fmaxf(u[mt][nt][0], u[mt][nt][1]),
                                 fmaxf(u[mt][nt][2], u[mt][nt][3])));
            const float e0 = __expf(__builtin_fmaf(u[mt][nt][0], DNRM, -dq));
            const float e1 = __expf(__builtin_fmaf(u[mt][nt][1], DNRM, -dq));
            const float e2 = __expf(__builtin_fmaf(u[mt][nt][2], DNRM, -dq));
            const float e3 = __expf(__builtin_fmaf(u[mt][nt][3], DNRM, -dq));
            const int mb = (4 * w + mt) * 16 + 4 * q;
            np += e0 * knr[mt][0] + e1 * knr[mt][1] + e2 * knr[mt][2] +
                  e3 * knr[mt][3];
            *(short4*)&PHT[nt * 16 + c][mb] = make_short4(
                (short)f2b(e0), (short)f2b(e1), (short)f2b(e2), (short)f2b(e3));
        }
        np += __shfl_xor(np, 16, 64);
        np += __shfl_xor(np, 32, 64);
        vm = fmaxf(vm, __shfl_xor(vm, 16, 64));
        vm = fmaxf(vm, __shfl_xor(vm, 32, 64));
        if (q == 0) {
            npart[w][nt * 16 + c] = np;
            cw[w][nt * 16 + c] = vm;
        }
    }
    __syncthreads();
    // PV GEMM: wave w owns n-tile w; kvT B-frags from global (L2-hot)
    f32x4 acc[4];
#pragma unroll
    for (int dt = 0; dt < 4; ++dt) acc[dt] = (f32x4){0.f, 0.f, 0.f, 0.f};
#pragma unroll
    for (int kc = 0; kc < 8; ++kc) {
        const s16x8 a = *(const s16x8*)&PHT[w * 16 + c][kc * 32 + q * 8];
#pragma unroll
        for (int dt = 0; dt < 4; ++dt) {
            const s16x8 b =
                *(const s16x8*)&kvT[(size_t)(dt * 16 + c) * 256 + kc * 32 + q * 8];
            acc[dt] = __builtin_amdgcn_mfma_f32_16x16x32_bf16(a, b, acc[dt], 0, 0, 0);
        }
    }
    __syncthreads();  // PHT reads done; reuse as fp32 out tile [64][68]
    float* ot = (float*)&PHT[0][0];
    float rn[4], gm[4];
#pragma unroll
    for (int r = 0; r < 4; ++r) {
        const int nl = w * 16 + 4 * q + r;
        const float npsum = (npart[0][nl] + npart[1][nl]) +
                            (npart[2][nl] + npart[3][nl]);
        const float st =
            fmaxf(fmaxf(cw[0][nl], cw[1][nl]), fmaxf(cw[2][nl], cw[3][nl]));
        const float gamma = EPSV * __expf(st * DNRM);  // eps * e^{stab_n}
        gm[r] = gamma;
        rn[r] = 1.0f / (npsum + gamma * Ts);
    }
#pragma unroll
    for (int dt = 0; dt < 4; ++dt)
#pragma unroll
        for (int r = 0; r < 4; ++r)
            ot[(dt * 16 + c) * 68 + (w * 16 + 4 * q + r)] =
                (acc[dt][r] + gm[r] * Sl[dt * 16 + c]) * rn[r];
    __syncthreads();
    float* op = out + (size_t)bh * Dv * Nv;
    {
        const int d = tid >> 2, ng = (tid & 3) * 16;
#pragma unroll
        for (int i = 0; i < 4; ++i) {
            const float4 v = *(const float4*)&ot[d * 68 + ng + i * 4];
            *(float4*)&op[d * Nv + n0 + ng + i * 4] = v;
        }
    }
}

// ---------------------------------------------------------------------------
extern "C" void kernel_launch(void* const* d_in, const int* in_sizes, int n_in,
                              void* d_out, int out_size, void* d_ws, size_t ws_size,
                              hipStream_t stream) {
    const float* q = (const float*)d_in[0];
    const float* k = (const float*)d_in[1];
    const float* v = (const float*)d_in[2];
    const float* proj = (const float*)d_in[3];
    float* ws = (float*)d_ws;
    float* out = (float*)d_out;

    hipMemsetAsync(ws, 0, (size_t)ZERO_FLOATS * sizeof(float), stream);
    favor_kv<<<dim3(SPL, 32), 256, 0, stream>>>(k, v, proj, ws);
    favor_kvred<<<dim3(16, 32), 256, 0, stream>>>(ws);
    favor_out<<<dim3(Nv / 64, 32), 256, 0, stream>>>(q, proj, ws, out);
}

// Round 8
// 324.791 us; speedup vs baseline: 1.0876x; 1.0876x over previous
//
#include <hip/hip_runtime.h>

// FavorAttention (Performer FAVOR+) — B=4,H=8,D=64,N=8192,M=256, fp32 in/out.
// R9: memory duty-cycle attack.
// kv: raw-barrier pipeline. HIP __syncthreads drains vmcnt(0) (killed R8's
// prefetch). Replace in-loop barriers with {s_waitcnt lgkmcnt(0); s_barrier;
// sched_barrier(0)} — LDS-visibility only, vmcnt untouched — so next chunk's
// global loads stay in flight across barriers and land under compute.
// out: PV read kvT via 32 dependent L2 loads/thread; now kvT (32 KB/bh) is
// staged to LDS ([64][264] pad, conflict-free) at block start, issued after
// the Q loads (Q staging waits vmcnt(8), kvT still flying). LDS 70.4 KB ->
// 2 blocks/CU — acceptable: occupancy 29->38% previously moved nothing.
// Keeps R8 math: KSTAB=15 const k-stabilizer, gamma-algebra q-side (no mid
// stabilizer), SD/T atomics in kvred.

typedef short s16x8 __attribute__((ext_vector_type(8)));
typedef float f32x4 __attribute__((ext_vector_type(4)));

#define Dv 64
#define Nv 8192
#define Mv 256
#define BHv 32
#define SPL 16
#define NSPL (Nv / SPL)   // 512
#define NCH (NSPL / 64)   // 8

#define DNRM 0.3535533905932738f   // 64^-0.25
#define EPSV 1e-6f
#define KSTAB 15.0f                // constant k-side working stabilizer

// raw barrier: LDS drain + wave sync, NO vmcnt drain (prefetch survives)
#define BARRIER_RAW()                                        \
    do {                                                     \
        asm volatile("s_waitcnt lgkmcnt(0)" ::: "memory");   \
        __builtin_amdgcn_s_barrier();                        \
        __builtin_amdgcn_sched_barrier(0);                   \
    } while (0)

// ws layout (float offsets)
#define OFF_SD 0                                // [32][64] Sum_m kv (atomic)
#define OFF_T (OFF_SD + BHv * Dv)               // [32] Sum_m key_norm (atomic)
#define OFF_SGM (OFF_T + BHv)                   // [32][16][4] per-(split,wave) sigma
#define OFF_SVP (OFF_SGM + BHv * SPL * 4)       // [32][16][64] V col-sum partials
#define OFF_KNP (OFF_SVP + BHv * SPL * 64)      // [32][16][256]
#define OFF_KNF (OFF_KNP + BHv * SPL * Mv)      // [32][256]
#define OFF_KVP (OFF_KNF + BHv * Mv)            // [32][16][256][64] fp32
#define OFF_KVT (OFF_KVP + BHv * SPL * Mv * Dv) // [32][64][256] bf16
#define ZERO_FLOATS (OFF_SGM)                   // memset SD+T region

__device__ __forceinline__ unsigned short f2b(float x) {
    return __builtin_bit_cast(unsigned short, (__bf16)x);
}

__device__ __forceinline__ s16x8 load_pfrag(const float* __restrict__ proj, int m,
                                            int kc, int q) {
    const float* p = proj + m * 64 + kc * 32 + q * 8;
    s16x8 r;
#pragma unroll
    for (int j = 0; j < 8; ++j) r[j] = (short)f2b(p[j]);
    return r;
}

// ---------------------------------------------------------------------------
// kv: 256 threads. Per chunk: stage regs->LDS, issue next chunk's loads (stay
// in flight across RAW barriers, land under compute), GEMM1 -> exp -> GEMM2.
__global__ __launch_bounds__(256, 2) void favor_kv(const float* __restrict__ key,
                                                   const float* __restrict__ value,
                                                   const float* __restrict__ proj,
                                                   float* __restrict__ ws) {
    __shared__ __align__(16) unsigned short KT[64][72];   // [n][d]
    __shared__ __align__(16) unsigned short VL[64][72];   // [d][n]
    __shared__ __align__(16) unsigned short PH[256][40];  // [m][32n half] phi
    __shared__ __align__(16) float dred[16][64];          // diag partials [g][n]
    __shared__ __align__(16) float dgl[64];               // diag_k + KSTAB
    const int tid = threadIdx.x;
    const int w = tid >> 6, l = tid & 63, c = l & 15, q = l >> 4;
    const int g = tid >> 4, cs = tid & 15;
    const int s = blockIdx.x, bh = blockIdx.y;
    const float* kp = key + (size_t)bh * Dv * Nv;
    const float* vp = value + (size_t)bh * Dv * Nv;

    s16x8 P[4][2];
#pragma unroll
    for (int mt = 0; mt < 4; ++mt)
#pragma unroll
        for (int kc = 0; kc < 2; ++kc)
            P[mt][kc] = load_pfrag(proj, (4 * w + mt) * 16 + c, kc, q);

    f32x4 kva[4][4];
#pragma unroll
    for (int mt = 0; mt < 4; ++mt)
#pragma unroll
        for (int dt = 0; dt < 4; ++dt) kva[mt][dt] = (f32x4){0.f, 0.f, 0.f, 0.f};
    float kn[4] = {0.f, 0.f, 0.f, 0.f};
    float sv[4] = {0.f, 0.f, 0.f, 0.f};
    float tmax = -3.0e38f;

    // prologue: load chunk 0 into regs
    float4 kk[4], vv[4];
    {
        const int n0 = s * NSPL;
#pragma unroll
        for (int di = 0; di < 4; ++di) {
            kk[di] = *(const float4*)&kp[(4 * g + di) * Nv + n0 + 4 * cs];
            vv[di] = *(const float4*)&vp[(4 * g + di) * Nv + n0 + 4 * cs];
        }
    }

    for (int ch = 0; ch < NCH; ++ch) {
        if (ch) BARRIER_RAW();  // B1: prev compute done; LDS safe to overwrite
        // stage current chunk from regs (compiler inserts vmcnt wait here)
#pragma unroll
        for (int j = 0; j < 4; ++j) {
            const float k0 = ((const float*)&kk[0])[j];
            const float k1 = ((const float*)&kk[1])[j];
            const float k2 = ((const float*)&kk[2])[j];
            const float k3 = ((const float*)&kk[3])[j];
            *(short4*)&KT[4 * cs + j][4 * g] =
                make_short4((short)f2b(k0), (short)f2b(k1), (short)f2b(k2),
                            (short)f2b(k3));
            dred[g][4 * cs + j] = (k0 * k0 + k1 * k1) + (k2 * k2 + k3 * k3);
        }
#pragma unroll
        for (int di = 0; di < 4; ++di) {
            *(short4*)&VL[4 * g + di][4 * cs] = make_short4(
                (short)f2b(vv[di].x), (short)f2b(vv[di].y),
                (short)f2b(vv[di].z), (short)f2b(vv[di].w));
            sv[di] += (vv[di].x + vv[di].y) + (vv[di].z + vv[di].w);
        }
        // issue next chunk's loads; they stay in flight across RAW barriers
        if (ch + 1 < NCH) {
            const int n1 = s * NSPL + (ch + 1) * 64;
#pragma unroll
            for (int di = 0; di < 4; ++di) {
                kk[di] = *(const float4*)&kp[(4 * g + di) * Nv + n1 + 4 * cs];
                vv[di] = *(const float4*)&vp[(4 * g + di) * Nv + n1 + 4 * cs];
            }
        }
        BARRIER_RAW();  // B2: staging visible (lgkm only; vmcnt untouched)
        if (tid < 64) {
            float ds = 0.f;
#pragma unroll
            for (int gg = 0; gg < 16; ++gg) ds += dred[gg][tid];
            dgl[tid] = ds * 0.0625f + KSTAB;  // exp arg = u*DNRM - dgl
        }
        BARRIER_RAW();  // B3: dgl visible
#pragma unroll
        for (int h = 0; h < 2; ++h) {
#pragma unroll
            for (int nt2 = 0; nt2 < 2; ++nt2) {
                const int nt = 2 * h + nt2;
                const s16x8 a0 = *(const s16x8*)&KT[nt * 16 + c][q * 8];
                const s16x8 a1 = *(const s16x8*)&KT[nt * 16 + c][32 + q * 8];
                const float4 dg = *(const float4*)&dgl[nt * 16 + q * 4];
#pragma unroll
                for (int mt = 0; mt < 4; ++mt) {
                    f32x4 u = {0.f, 0.f, 0.f, 0.f};
                    u = __builtin_amdgcn_mfma_f32_16x16x32_bf16(a0, P[mt][0], u, 0, 0, 0);
                    u = __builtin_amdgcn_mfma_f32_16x16x32_bf16(a1, P[mt][1], u, 0, 0, 0);
                    tmax = fmaxf(tmax, fmaxf(fmaxf(u[0], u[1]), fmaxf(u[2], u[3])));
                    const float e0 = __expf(__builtin_fmaf(u[0], DNRM, -dg.x));
                    const float e1 = __expf(__builtin_fmaf(u[1], DNRM, -dg.y));
                    const float e2 = __expf(__builtin_fmaf(u[2], DNRM, -dg.z));
                    const float e3 = __expf(__builtin_fmaf(u[3], DNRM, -dg.w));
                    kn[mt] += (e0 + e1) + (e2 + e3);
                    *(short4*)&PH[(4 * w + mt) * 16 + c][nt2 * 16 + q * 4] =
                        make_short4((short)f2b(e0), (short)f2b(e1),
                                    (short)f2b(e2), (short)f2b(e3));
                }
            }
            s16x8 bf[4];
#pragma unroll
            for (int dt = 0; dt < 4; ++dt)
                bf[dt] = *(const s16x8*)&VL[dt * 16 + c][h * 32 + q * 8];
#pragma unroll
            for (int mt = 0; mt < 4; ++mt) {
                const s16x8 a = *(const s16x8*)&PH[(4 * w + mt) * 16 + c][q * 8];
#pragma unroll
                for (int dt = 0; dt < 4; ++dt)
                    kva[mt][dt] = __builtin_amdgcn_mfma_f32_16x16x32_bf16(
                        a, bf[dt], kva[mt][dt], 0, 0, 0);
            }
        }
    }
    // sigma = true per-wave raw max * DNRM (one reduce per kernel)
#pragma unroll
    for (int off = 1; off < 64; off <<= 1)
        tmax = fmaxf(tmax, __shfl_xor(tmax, off, 64));
    if (l == 0) ws[OFF_SGM + (bh * SPL + s) * 4 + w] = tmax * DNRM;
    float* kvp = ws + OFF_KVP + (size_t)(bh * SPL + s) * Mv * Dv;
#pragma unroll
    for (int mt = 0; mt < 4; ++mt) {
        const int mrow = (4 * w + mt) * 16 + 4 * q;
#pragma unroll
        for (int dt = 0; dt < 4; ++dt) {
            const int dcol = dt * 16 + c;
#pragma unroll
            for (int r = 0; r < 4; ++r)
                kvp[(size_t)(mrow + r) * Dv + dcol] = kva[mt][dt][r];
        }
    }
#pragma unroll
    for (int mt = 0; mt < 4; ++mt) {
        kn[mt] += __shfl_xor(kn[mt], 16, 64);
        kn[mt] += __shfl_xor(kn[mt], 32, 64);
    }
    if (q == 0) {
        float* knp = ws + OFF_KNP + (bh * SPL + s) * Mv;
#pragma unroll
        for (int mt = 0; mt < 4; ++mt) knp[(4 * w + mt) * 16 + c] = kn[mt];
    }
    // V col-sum reduce (reuse dred region; full __syncthreads is fine here)
    __syncthreads();
    float* sp = &dred[0][0];  // as [64][16]
#pragma unroll
    for (int di = 0; di < 4; ++di) sp[(4 * g + di) * 16 + cs] = sv[di];
    __syncthreads();
    if (tid < 64) {
        float t2 = 0.f;
#pragma unroll
        for (int j = 0; j < 16; ++j) t2 += sp[tid * 16 + j];
        ws[OFF_SVP + (bh * SPL + s) * 64 + tid] = t2;
    }
}

// ---------------------------------------------------------------------------
// reduce split partials, uniform alpha = exp(KSTAB - G); add eps terms.
// Also accumulates S_d = Sum_m kv[m][d] and T = Sum_m key_norm[m] (atomics).
__global__ __launch_bounds__(256) void favor_kvred(float* __restrict__ ws) {
    __shared__ float sAl;
    __shared__ float svl[64];
    const int t = threadIdx.x, f = blockIdx.x, bh = blockIdx.y;
    const int flat = f * 1024 + t * 4;
    const int m = flat >> 6, d0 = flat & 63;
    if (t < 64) {
        float v = ws[OFF_SGM + bh * 64 + t];
#pragma unroll
        for (int off = 1; off < 64; off <<= 1)
            v = fmaxf(v, __shfl_xor(v, off, 64));
        if (t == 0) sAl = __expf(KSTAB - v);
    } else if (t < 128) {
        const int d = t - 64;
        float x = 0.f;
#pragma unroll
        for (int s2 = 0; s2 < SPL; ++s2)
            x += ws[OFF_SVP + (bh * SPL + s2) * 64 + d];
        svl[d] = x;
    }
    __syncthreads();
    const float al = sAl;
    float4 acc = make_float4(0.f, 0.f, 0.f, 0.f);
    for (int s2 = 0; s2 < SPL; ++s2) {
        const float4 v =
            *(const float4*)&ws[OFF_KVP + ((size_t)(bh * SPL + s2) << 14) + flat];
        acc.x += v.x; acc.y += v.y; acc.z += v.z; acc.w += v.w;
    }
    acc.x = acc.x * al + EPSV * svl[d0 + 0];
    acc.y = acc.y * al + EPSV * svl[d0 + 1];
    acc.z = acc.z * al + EPSV * svl[d0 + 2];
    acc.w = acc.w * al + EPSV * svl[d0 + 3];
    unsigned short* kvT = (unsigned short*)(ws + OFF_KVT);
    kvT[(bh * 64 + d0 + 0) * 256 + m] = f2b(acc.x);
    kvT[(bh * 64 + d0 + 1) * 256 + m] = f2b(acc.y);
    kvT[(bh * 64 + d0 + 2) * 256 + m] = f2b(acc.z);
    kvT[(bh * 64 + d0 + 3) * 256 + m] = f2b(acc.w);
    atomicAdd(&ws[OFF_SD + bh * 64 + d0 + 0], acc.x);
    atomicAdd(&ws[OFF_SD + bh * 64 + d0 + 1], acc.y);
    atomicAdd(&ws[OFF_SD + bh * 64 + d0 + 2], acc.z);
    atomicAdd(&ws[OFF_SD + bh * 64 + d0 + 3], acc.w);
    if (t < 16) {
        const int mm = f * 16 + t;
        float kk = 0.f;
        for (int s2 = 0; s2 < SPL; ++s2)
            kk += ws[OFF_KNP + (bh * SPL + s2) * Mv + mm];
        const float knf = kk * al + EPSV * (float)Nv;
        ws[OFF_KNF + bh * Mv + mm] = knf;
        atomicAdd(&ws[OFF_T + bh], knf);
    }
}

// ---------------------------------------------------------------------------
// out: issue Q loads, then kvT loads (kvT flies while Q stages at vmcnt(8));
// kvT -> KVL LDS (padded, conflict-free) so PV is pure ds_read_b128; exp with
// NO stabilizer + free per-token max; normalize with gamma = eps*exp(stab_n).
__global__ __launch_bounds__(256, 2) void favor_out(const float* __restrict__ query,
                                                    const float* __restrict__ proj,
                                                    const float* __restrict__ ws,
                                                    float* __restrict__ out) {
    __shared__ __align__(16) unsigned short PHT[64][264];  // phi^T (aliased)
    __shared__ __align__(16) unsigned short KVL[64][264];  // kvT staged [d][m]
    __shared__ float npart[4][64];
    __shared__ float knl[256];
    __shared__ float cw[4][64];  // per-wave col-max (raw u)
    __shared__ float dql[64];
    __shared__ float Sl[64];
    __shared__ float Ts;
    // aliases inside PHT region (dead before first PHT write):
    unsigned short (*QT)[72] = (unsigned short (*)[72]) & PHT[0][0];  // 9216 B
    float (*dred)[64] = (float (*)[64])((char*)&PHT[0][0] + 9216);    // 4096 B
    const int tid = threadIdx.x;
    const int w = tid >> 6, l = tid & 63, c = l & 15, q = l >> 4;
    const int g = tid >> 4, cs = tid & 15;
    const int nb = blockIdx.x, bh = blockIdx.y;
    const int n0 = nb * 64;
    const float* qp = query + (size_t)bh * Dv * Nv;
    const uint4* kvg = (const uint4*)((const unsigned short*)(ws + OFF_KVT) +
                                      (size_t)bh * 64 * 256);

    // issue Q loads FIRST, then kvT loads: Q staging waits vmcnt(8),
    // kvT still in flight under it.
    float4 qq[4];
#pragma unroll
    for (int di = 0; di < 4; ++di)
        qq[di] = *(const float4*)&qp[(4 * g + di) * Nv + n0 + 4 * cs];
    uint4 kvr[8];
#pragma unroll
    for (int i = 0; i < 8; ++i) kvr[i] = kvg[i * 256 + tid];

    // stage Q transposed + diag_q partials
#pragma unroll
    for (int j = 0; j < 4; ++j) {
        const float v0 = ((const float*)&qq[0])[j];
        const float v1 = ((const float*)&qq[1])[j];
        const float v2 = ((const float*)&qq[2])[j];
        const float v3 = ((const float*)&qq[3])[j];
        *(short4*)&QT[4 * cs + j][4 * g] =
            make_short4((short)f2b(v0), (short)f2b(v1), (short)f2b(v2),
                        (short)f2b(v3));
        dred[g][4 * cs + j] = (v0 * v0 + v1 * v1) + (v2 * v2 + v3 * v3);
    }
    // stage kvT -> KVL (uint4 j covers row j>>5, elems (j&31)*8..+7)
#pragma unroll
    for (int i = 0; i < 8; ++i) {
        const int j = i * 256 + tid;
        *(uint4*)&KVL[j >> 5][(j & 31) * 8] = kvr[i];
    }
    knl[tid] = ws[OFF_KNF + bh * Mv + tid];
    if (tid < 64) Sl[tid] = ws[OFF_SD + bh * 64 + tid];
    if (tid == 0) Ts = ws[OFF_T + bh];

    s16x8 P[4][2];
#pragma unroll
    for (int mt = 0; mt < 4; ++mt)
#pragma unroll
        for (int kc = 0; kc < 2; ++kc)
            P[mt][kc] = load_pfrag(proj, (4 * w + mt) * 16 + c, kc, q);
    __syncthreads();

    // dql compute (tid<64) overlaps GEMM_uq on the other threads
    if (tid < 64) {
        float dsum = 0.f;
#pragma unroll
        for (int gg = 0; gg < 16; ++gg) dsum += dred[gg][tid];
        dql[tid] = dsum * 0.0625f;
    }
    float knr[4][4];
#pragma unroll
    for (int mt = 0; mt < 4; ++mt) {
        const int mb = (4 * w + mt) * 16 + 4 * q;
#pragma unroll
        for (int r = 0; r < 4; ++r) knr[mt][r] = knl[mb + r];
    }

    // GEMM_uq: D[m][n], wave w owns m = 64w..64w+63
    f32x4 u[4][4];
#pragma unroll
    for (int mt = 0; mt < 4; ++mt)
#pragma unroll
        for (int nt = 0; nt < 4; ++nt) u[mt][nt] = (f32x4){0.f, 0.f, 0.f, 0.f};
#pragma unroll
    for (int nt = 0; nt < 4; ++nt) {
        const s16x8 b0 = *(const s16x8*)&QT[nt * 16 + c][q * 8];
        const s16x8 b1 = *(const s16x8*)&QT[nt * 16 + c][32 + q * 8];
#pragma unroll
        for (int mt = 0; mt < 4; ++mt) {
            u[mt][nt] =
                __builtin_amdgcn_mfma_f32_16x16x32_bf16(P[mt][0], b0, u[mt][nt], 0, 0, 0);
            u[mt][nt] =
                __builtin_amdgcn_mfma_f32_16x16x32_bf16(P[mt][1], b1, u[mt][nt], 0, 0, 0);
        }
    }
    __syncthreads();  // dql ready; QT/dred reads done -> PHT writes safe
    // exp (no stabilizer) -> PHT + np partials + free col-max tracking
#pragma unroll
    for (int nt = 0; nt < 4; ++nt) {
        const float dq = dql[nt * 16 + c];
        float np = 0.f;
        float vm = -3.4e38f;
#pragma unroll
        for (int mt = 0; mt < 4; ++mt) {
            vm = fmaxf(vm, fmaxf(fmaxf(u[mt][nt][0], u[mt][nt][1]),
                                 fmaxf(u[mt][nt][2], u[mt][nt][3])));
            const float e0 = __expf(__builtin_fmaf(u[mt][nt][0], DNRM, -dq));
            const float e1 = __expf(__builtin_fmaf(u[mt][nt][1], DNRM, -dq));
            const float e2 = __expf(__builtin_fmaf(u[mt][nt][2], DNRM, -dq));
            const float e3 = __expf(__builtin_fmaf(u[mt][nt][3], DNRM, -dq));
            const int mb = (4 * w + mt) * 16 + 4 * q;
            np += e0 * knr[mt][0] + e1 * knr[mt][1] + e2 * knr[mt][2] +
                  e3 * knr[mt][3];
            *(short4*)&PHT[nt * 16 + c][mb] = make_short4(
                (short)f2b(e0), (short)f2b(e1), (short)f2b(e2), (short)f2b(e3));
        }
        np += __shfl_xor(np, 16, 64);
        np += __shfl_xor(np, 32, 64);
        vm = fmaxf(vm, __shfl_xor(vm, 16, 64));
        vm = fmaxf(vm, __shfl_xor(vm, 32, 64));
        if (q == 0) {
            npart[w][nt * 16 + c] = np;
            cw[w][nt * 16 + c] = vm;
        }
    }
    __syncthreads();
    // PV GEMM: wave w owns n-tile w; B-frags now pure LDS ds_read_b128
    f32x4 acc[4];
#pragma unroll
    for (int dt = 0; dt < 4; ++dt) acc[dt] = (f32x4){0.f, 0.f, 0.f, 0.f};
#pragma unroll
    for (int kc = 0; kc < 8; ++kc) {
        const s16x8 a = *(const s16x8*)&PHT[w * 16 + c][kc * 32 + q * 8];
#pragma unroll
        for (int dt = 0; dt < 4; ++dt) {
            const s16x8 b = *(const s16x8*)&KVL[dt * 16 + c][kc * 32 + q * 8];
            acc[dt] = __builtin_amdgcn_mfma_f32_16x16x32_bf16(a, b, acc[dt], 0, 0, 0);
        }
    }
    __syncthreads();  // PHT reads done; reuse as fp32 out tile [64][68]
    float* ot = (float*)&PHT[0][0];
    float rn[4], gm[4];
#pragma unroll
    for (int r = 0; r < 4; ++r) {
        const int nl = w * 16 + 4 * q + r;
        const float npsum = (npart[0][nl] + npart[1][nl]) +
                            (npart[2][nl] + npart[3][nl]);
        const float st =
            fmaxf(fmaxf(cw[0][nl], cw[1][nl]), fmaxf(cw[2][nl], cw[3][nl]));
        const float gamma = EPSV * __expf(st * DNRM);  // eps * e^{stab_n}
        gm[r] = gamma;
        rn[r] = 1.0f / (npsum + gamma * Ts);
    }
#pragma unroll
    for (int dt = 0; dt < 4; ++dt)
#pragma unroll
        for (int r = 0; r < 4; ++r)
            ot[(dt * 16 + c) * 68 + (w * 16 + 4 * q + r)] =
                (acc[dt][r] + gm[r] * Sl[dt * 16 + c]) * rn[r];
    __syncthreads();
    float* op = out + (size_t)bh * Dv * Nv;
    {
        const int d = tid >> 2, ng = (tid & 3) * 16;
#pragma unroll
        for (int i = 0; i < 4; ++i) {
            const float4 v = *(const float4*)&ot[d * 68 + ng + i * 4];
            *(float4*)&op[d * Nv + n0 + ng + i * 4] = v;
        }
    }
}

// ---------------------------------------------------------------------------
extern "C" void kernel_launch(void* const* d_in, const int* in_sizes, int n_in,
                              void* d_out, int out_size, void* d_ws, size_t ws_size,
                              hipStream_t stream) {
    const float* q = (const float*)d_in[0];
    const float* k = (const float*)d_in[1];
    const float* v = (const float*)d_in[2];
    const float* proj = (const float*)d_in[3];
    float* ws = (float*)d_ws;
    float* out = (float*)d_out;

    hipMemsetAsync(ws, 0, (size_t)ZERO_FLOATS * sizeof(float), stream);
    favor_kv<<<dim3(SPL, 32), 256, 0, stream>>>(k, v, proj, ws);
    favor_kvred<<<dim3(16, 32), 256, 0, stream>>>(ws);
    favor_out<<<dim3(Nv / 64, 32), 256, 0, stream>>>(q, proj, ws, out);
}

// Round 9
// 279.995 us; speedup vs baseline: 1.2616x; 1.1600x over previous
//
#include <hip/hip_runtime.h>

// FavorAttention (Performer FAVOR+) — B=4,H=8,D=64,N=8192,M=256, fp32 in/out.
// R10: amortization pass on top of R9 (which cut favor_out 118->86 via KVL
// staging + issue-early loads + raw barriers).
// out: 2 n-tiles per block (grid 4096->2048). kvT staging / P frags / knl
// paid once per 2 tiles; tile-1 Q loads issued at kernel entry and land
// under tile-0 compute (raw lgkm-only barriers keep them in flight).
// Sl = Sum_m kv[m][d] and Ts = Sum_m key_norm computed IN-LDS from staged
// KVL/knl (wave 1 + lane 128, overlapping GEMM_uq like dql on wave 0) —
// kvred loses its atomics, launcher loses the memset dispatch.
// kv / kvred math unchanged: KSTAB=15, sigma per (split,wave), uniform
// alpha=exp(KSTAB-G); q-side gamma-algebra (no mid-kernel stabilizer).

typedef short s16x8 __attribute__((ext_vector_type(8)));
typedef float f32x4 __attribute__((ext_vector_type(4)));

#define Dv 64
#define Nv 8192
#define Mv 256
#define BHv 32
#define SPL 16
#define NSPL (Nv / SPL)   // 512
#define NCH (NSPL / 64)   // 8

#define DNRM 0.3535533905932738f   // 64^-0.25
#define EPSV 1e-6f
#define KSTAB 15.0f                // constant k-side working stabilizer

// raw barrier: LDS drain + wave sync, NO vmcnt drain (prefetch survives)
#define BARRIER_RAW()                                        \
    do {                                                     \
        asm volatile("s_waitcnt lgkmcnt(0)" ::: "memory");   \
        __builtin_amdgcn_s_barrier();                        \
        __builtin_amdgcn_sched_barrier(0);                   \
    } while (0)

// ws layout (float offsets)
#define OFF_SGM 0                               // [32][16][4] per-(split,wave) sigma
#define OFF_SVP (OFF_SGM + BHv * SPL * 4)       // [32][16][64] V col-sum partials
#define OFF_KNP (OFF_SVP + BHv * SPL * 64)      // [32][16][256]
#define OFF_KNF (OFF_KNP + BHv * SPL * Mv)      // [32][256]
#define OFF_KVP (OFF_KNF + BHv * Mv)            // [32][16][256][64] fp32
#define OFF_KVT (OFF_KVP + BHv * SPL * Mv * Dv) // [32][64][256] bf16

__device__ __forceinline__ unsigned short f2b(float x) {
    return __builtin_bit_cast(unsigned short, (__bf16)x);
}
__device__ __forceinline__ float b2f(unsigned short u) {
    const unsigned int v = ((unsigned int)u) << 16;
    return __builtin_bit_cast(float, v);
}

__device__ __forceinline__ s16x8 load_pfrag(const float* __restrict__ proj, int m,
                                            int kc, int q) {
    const float* p = proj + m * 64 + kc * 32 + q * 8;
    s16x8 r;
#pragma unroll
    for (int j = 0; j < 8; ++j) r[j] = (short)f2b(p[j]);
    return r;
}

// ---------------------------------------------------------------------------
// kv: 256 threads. Per chunk: stage regs->LDS, issue next chunk's loads (stay
// in flight across RAW barriers, land under compute), GEMM1 -> exp -> GEMM2.
__global__ __launch_bounds__(256, 2) void favor_kv(const float* __restrict__ key,
                                                   const float* __restrict__ value,
                                                   const float* __restrict__ proj,
                                                   float* __restrict__ ws) {
    __shared__ __align__(16) unsigned short KT[64][72];   // [n][d]
    __shared__ __align__(16) unsigned short VL[64][72];   // [d][n]
    __shared__ __align__(16) unsigned short PH[256][40];  // [m][32n half] phi
    __shared__ __align__(16) float dred[16][64];          // diag partials [g][n]
    __shared__ __align__(16) float dgl[64];               // diag_k + KSTAB
    const int tid = threadIdx.x;
    const int w = tid >> 6, l = tid & 63, c = l & 15, q = l >> 4;
    const int g = tid >> 4, cs = tid & 15;
    const int s = blockIdx.x, bh = blockIdx.y;
    const float* kp = key + (size_t)bh * Dv * Nv;
    const float* vp = value + (size_t)bh * Dv * Nv;

    s16x8 P[4][2];
#pragma unroll
    for (int mt = 0; mt < 4; ++mt)
#pragma unroll
        for (int kc = 0; kc < 2; ++kc)
            P[mt][kc] = load_pfrag(proj, (4 * w + mt) * 16 + c, kc, q);

    f32x4 kva[4][4];
#pragma unroll
    for (int mt = 0; mt < 4; ++mt)
#pragma unroll
        for (int dt = 0; dt < 4; ++dt) kva[mt][dt] = (f32x4){0.f, 0.f, 0.f, 0.f};
    float kn[4] = {0.f, 0.f, 0.f, 0.f};
    float sv[4] = {0.f, 0.f, 0.f, 0.f};
    float tmax = -3.0e38f;

    // prologue: load chunk 0 into regs
    float4 kk[4], vv[4];
    {
        const int n0 = s * NSPL;
#pragma unroll
        for (int di = 0; di < 4; ++di) {
            kk[di] = *(const float4*)&kp[(4 * g + di) * Nv + n0 + 4 * cs];
            vv[di] = *(const float4*)&vp[(4 * g + di) * Nv + n0 + 4 * cs];
        }
    }

    for (int ch = 0; ch < NCH; ++ch) {
        if (ch) BARRIER_RAW();  // B1: prev compute done; LDS safe to overwrite
        // stage current chunk from regs (compiler inserts vmcnt wait here)
#pragma unroll
        for (int j = 0; j < 4; ++j) {
            const float k0 = ((const float*)&kk[0])[j];
            const float k1 = ((const float*)&kk[1])[j];
            const float k2 = ((const float*)&kk[2])[j];
            const float k3 = ((const float*)&kk[3])[j];
            *(short4*)&KT[4 * cs + j][4 * g] =
                make_short4((short)f2b(k0), (short)f2b(k1), (short)f2b(k2),
                            (short)f2b(k3));
            dred[g][4 * cs + j] = (k0 * k0 + k1 * k1) + (k2 * k2 + k3 * k3);
        }
#pragma unroll
        for (int di = 0; di < 4; ++di) {
            *(short4*)&VL[4 * g + di][4 * cs] = make_short4(
                (short)f2b(vv[di].x), (short)f2b(vv[di].y),
                (short)f2b(vv[di].z), (short)f2b(vv[di].w));
            sv[di] += (vv[di].x + vv[di].y) + (vv[di].z + vv[di].w);
        }
        // issue next chunk's loads; they stay in flight across RAW barriers
        if (ch + 1 < NCH) {
            const int n1 = s * NSPL + (ch + 1) * 64;
#pragma unroll
            for (int di = 0; di < 4; ++di) {
                kk[di] = *(const float4*)&kp[(4 * g + di) * Nv + n1 + 4 * cs];
                vv[di] = *(const float4*)&vp[(4 * g + di) * Nv + n1 + 4 * cs];
            }
        }
        BARRIER_RAW();  // B2: staging visible (lgkm only; vmcnt untouched)
        if (tid < 64) {
            float ds = 0.f;
#pragma unroll
            for (int gg = 0; gg < 16; ++gg) ds += dred[gg][tid];
            dgl[tid] = ds * 0.0625f + KSTAB;  // exp arg = u*DNRM - dgl
        }
        BARRIER_RAW();  // B3: dgl visible
#pragma unroll
        for (int h = 0; h < 2; ++h) {
#pragma unroll
            for (int nt2 = 0; nt2 < 2; ++nt2) {
                const int nt = 2 * h + nt2;
                const s16x8 a0 = *(const s16x8*)&KT[nt * 16 + c][q * 8];
                const s16x8 a1 = *(const s16x8*)&KT[nt * 16 + c][32 + q * 8];
                const float4 dg = *(const float4*)&dgl[nt * 16 + q * 4];
#pragma unroll
                for (int mt = 0; mt < 4; ++mt) {
                    f32x4 u = {0.f, 0.f, 0.f, 0.f};
                    u = __builtin_amdgcn_mfma_f32_16x16x32_bf16(a0, P[mt][0], u, 0, 0, 0);
                    u = __builtin_amdgcn_mfma_f32_16x16x32_bf16(a1, P[mt][1], u, 0, 0, 0);
                    tmax = fmaxf(tmax, fmaxf(fmaxf(u[0], u[1]), fmaxf(u[2], u[3])));
                    const float e0 = __expf(__builtin_fmaf(u[0], DNRM, -dg.x));
                    const float e1 = __expf(__builtin_fmaf(u[1], DNRM, -dg.y));
                    const float e2 = __expf(__builtin_fmaf(u[2], DNRM, -dg.z));
                    const float e3 = __expf(__builtin_fmaf(u[3], DNRM, -dg.w));
                    kn[mt] += (e0 + e1) + (e2 + e3);
                    *(short4*)&PH[(4 * w + mt) * 16 + c][nt2 * 16 + q * 4] =
                        make_short4((short)f2b(e0), (short)f2b(e1),
                                    (short)f2b(e2), (short)f2b(e3));
                }
            }
            s16x8 bf[4];
#pragma unroll
            for (int dt = 0; dt < 4; ++dt)
                bf[dt] = *(const s16x8*)&VL[dt * 16 + c][h * 32 + q * 8];
#pragma unroll
            for (int mt = 0; mt < 4; ++mt) {
                const s16x8 a = *(const s16x8*)&PH[(4 * w + mt) * 16 + c][q * 8];
#pragma unroll
                for (int dt = 0; dt < 4; ++dt)
                    kva[mt][dt] = __builtin_amdgcn_mfma_f32_16x16x32_bf16(
                        a, bf[dt], kva[mt][dt], 0, 0, 0);
            }
        }
    }
    // sigma = true per-wave raw max * DNRM (one reduce per kernel)
#pragma unroll
    for (int off = 1; off < 64; off <<= 1)
        tmax = fmaxf(tmax, __shfl_xor(tmax, off, 64));
    if (l == 0) ws[OFF_SGM + (bh * SPL + s) * 4 + w] = tmax * DNRM;
    float* kvp = ws + OFF_KVP + (size_t)(bh * SPL + s) * Mv * Dv;
#pragma unroll
    for (int mt = 0; mt < 4; ++mt) {
        const int mrow = (4 * w + mt) * 16 + 4 * q;
#pragma unroll
        for (int dt = 0; dt < 4; ++dt) {
            const int dcol = dt * 16 + c;
#pragma unroll
            for (int r = 0; r < 4; ++r)
                kvp[(size_t)(mrow + r) * Dv + dcol] = kva[mt][dt][r];
        }
    }
#pragma unroll
    for (int mt = 0; mt < 4; ++mt) {
        kn[mt] += __shfl_xor(kn[mt], 16, 64);
        kn[mt] += __shfl_xor(kn[mt], 32, 64);
    }
    if (q == 0) {
        float* knp = ws + OFF_KNP + (bh * SPL + s) * Mv;
#pragma unroll
        for (int mt = 0; mt < 4; ++mt) knp[(4 * w + mt) * 16 + c] = kn[mt];
    }
    // V col-sum reduce (reuse dred region; full __syncthreads is fine here)
    __syncthreads();
    float* sp = &dred[0][0];  // as [64][16]
#pragma unroll
    for (int di = 0; di < 4; ++di) sp[(4 * g + di) * 16 + cs] = sv[di];
    __syncthreads();
    if (tid < 64) {
        float t2 = 0.f;
#pragma unroll
        for (int j = 0; j < 16; ++j) t2 += sp[tid * 16 + j];
        ws[OFF_SVP + (bh * SPL + s) * 64 + tid] = t2;
    }
}

// ---------------------------------------------------------------------------
// reduce split partials, uniform alpha = exp(KSTAB - G); add eps terms.
// (R10: atomics removed — Sl/Ts now computed inside favor_out from LDS.)
__global__ __launch_bounds__(256) void favor_kvred(float* __restrict__ ws) {
    __shared__ float sAl;
    __shared__ float svl[64];
    const int t = threadIdx.x, f = blockIdx.x, bh = blockIdx.y;
    const int flat = f * 1024 + t * 4;
    const int m = flat >> 6, d0 = flat & 63;
    if (t < 64) {
        float v = ws[OFF_SGM + bh * 64 + t];
#pragma unroll
        for (int off = 1; off < 64; off <<= 1)
            v = fmaxf(v, __shfl_xor(v, off, 64));
        if (t == 0) sAl = __expf(KSTAB - v);
    } else if (t < 128) {
        const int d = t - 64;
        float x = 0.f;
#pragma unroll
        for (int s2 = 0; s2 < SPL; ++s2)
            x += ws[OFF_SVP + (bh * SPL + s2) * 64 + d];
        svl[d] = x;
    }
    __syncthreads();
    const float al = sAl;
    float4 acc = make_float4(0.f, 0.f, 0.f, 0.f);
    for (int s2 = 0; s2 < SPL; ++s2) {
        const float4 v =
            *(const float4*)&ws[OFF_KVP + ((size_t)(bh * SPL + s2) << 14) + flat];
        acc.x += v.x; acc.y += v.y; acc.z += v.z; acc.w += v.w;
    }
    acc.x = acc.x * al + EPSV * svl[d0 + 0];
    acc.y = acc.y * al + EPSV * svl[d0 + 1];
    acc.z = acc.z * al + EPSV * svl[d0 + 2];
    acc.w = acc.w * al + EPSV * svl[d0 + 3];
    unsigned short* kvT = (unsigned short*)(ws + OFF_KVT);
    kvT[(bh * 64 + d0 + 0) * 256 + m] = f2b(acc.x);
    kvT[(bh * 64 + d0 + 1) * 256 + m] = f2b(acc.y);
    kvT[(bh * 64 + d0 + 2) * 256 + m] = f2b(acc.z);
    kvT[(bh * 64 + d0 + 3) * 256 + m] = f2b(acc.w);
    if (t < 16) {
        const int mm = f * 16 + t;
        float kk = 0.f;
        for (int s2 = 0; s2 < SPL; ++s2)
            kk += ws[OFF_KNP + (bh * SPL + s2) * Mv + mm];
        ws[OFF_KNF + bh * Mv + mm] = kk * al + EPSV * (float)Nv;
    }
}

// ---------------------------------------------------------------------------
// out: 2 n-tiles per block. Entry: issue Q0, kvT, Q1 loads (vmcnt FIFO: Q0
// staging waits only its 4; kvT then stages; Q1 stays in flight across all of
// tile 0 via raw barriers). Sl/Ts from staged KVL/knl overlap GEMM_uq.
__global__ __launch_bounds__(256, 2) void favor_out(const float* __restrict__ query,
                                                    const float* __restrict__ proj,
                                                    const float* __restrict__ ws,
                                                    float* __restrict__ out) {
    __shared__ __align__(16) unsigned short PHT[64][264];  // phi^T (aliased)
    __shared__ __align__(16) unsigned short KVL[64][264];  // kvT staged [d][m]
    __shared__ float npart[4][64];
    __shared__ float knl[256];
    __shared__ float cw[4][64];  // per-wave col-max (raw u)
    __shared__ float dql[64];
    __shared__ float Sl[64];
    __shared__ float Tsh;
    // aliases inside PHT region (dead before first PHT write):
    unsigned short (*QT)[72] = (unsigned short (*)[72]) & PHT[0][0];  // 9216 B
    float (*dred)[64] = (float (*)[64])((char*)&PHT[0][0] + 9216);    // 4096 B
    const int tid = threadIdx.x;
    const int w = tid >> 6, l = tid & 63, c = l & 15, q = l >> 4;
    const int g = tid >> 4, cs = tid & 15;
    const int nb = blockIdx.x, bh = blockIdx.y;
    const int n0 = nb * 128;  // two 64-wide tiles
    const float* qp = query + (size_t)bh * Dv * Nv;
    const uint4* kvg = (const uint4*)((const unsigned short*)(ws + OFF_KVT) +
                                      (size_t)bh * 64 * 256);

    // issue order: Q tile0 (4), kvT (8), Q tile1 (4) — FIFO waits let each
    // stage start while later loads are still flying.
    float4 qqA[4], qqB[4];
#pragma unroll
    for (int di = 0; di < 4; ++di)
        qqA[di] = *(const float4*)&qp[(4 * g + di) * Nv + n0 + 4 * cs];
    uint4 kvr[8];
#pragma unroll
    for (int i = 0; i < 8; ++i) kvr[i] = kvg[i * 256 + tid];
#pragma unroll
    for (int di = 0; di < 4; ++di)
        qqB[di] = *(const float4*)&qp[(4 * g + di) * Nv + n0 + 64 + 4 * cs];

    // stage Q tile0 + dred
#pragma unroll
    for (int j = 0; j < 4; ++j) {
        const float v0 = ((const float*)&qqA[0])[j];
        const float v1 = ((const float*)&qqA[1])[j];
        const float v2 = ((const float*)&qqA[2])[j];
        const float v3 = ((const float*)&qqA[3])[j];
        *(short4*)&QT[4 * cs + j][4 * g] =
            make_short4((short)f2b(v0), (short)f2b(v1), (short)f2b(v2),
                        (short)f2b(v3));
        dred[g][4 * cs + j] = (v0 * v0 + v1 * v1) + (v2 * v2 + v3 * v3);
    }
    // stage kvT -> KVL (uint4 j covers row j>>5, elems (j&31)*8..+7)
#pragma unroll
    for (int i = 0; i < 8; ++i) {
        const int j = i * 256 + tid;
        *(uint4*)&KVL[j >> 5][(j & 31) * 8] = kvr[i];
    }
    knl[tid] = ws[OFF_KNF + bh * Mv + tid];

    s16x8 P[4][2];
#pragma unroll
    for (int mt = 0; mt < 4; ++mt)
#pragma unroll
        for (int kc = 0; kc < 2; ++kc)
            P[mt][kc] = load_pfrag(proj, (4 * w + mt) * 16 + c, kc, q);
    float knr[4][4];
    BARRIER_RAW();  // staging visible (qqB still in flight)
#pragma unroll
    for (int mt = 0; mt < 4; ++mt) {
        const int mb = (4 * w + mt) * 16 + 4 * q;
#pragma unroll
        for (int r = 0; r < 4; ++r) knr[mt][r] = knl[mb + r];
    }

    float* op = out + (size_t)bh * Dv * Nv;
#pragma unroll
    for (int t = 0; t < 2; ++t) {
        // wave0: dql; wave1: Sl (t==0); lane128: Ts (t==0); all overlap GEMM
        if (tid < 64) {
            float dsum = 0.f;
#pragma unroll
            for (int gg = 0; gg < 16; ++gg) dsum += dred[gg][tid];
            dql[tid] = dsum * 0.0625f;
        } else if (t == 0 && tid < 128) {
            const int d = tid - 64;
            float ssum = 0.f;
#pragma unroll
            for (int m2 = 0; m2 < 256; ++m2) ssum += b2f(KVL[d][m2]);
            Sl[d] = ssum;
        } else if (t == 0 && tid == 128) {
            float tsum = 0.f;
#pragma unroll
            for (int m2 = 0; m2 < 256; ++m2) tsum += knl[m2];
            Tsh = tsum;
        }
        // GEMM_uq: D[m][n], wave w owns m = 64w..64w+63
        f32x4 u[4][4];
#pragma unroll
        for (int mt = 0; mt < 4; ++mt)
#pragma unroll
            for (int nt = 0; nt < 4; ++nt) u[mt][nt] = (f32x4){0.f, 0.f, 0.f, 0.f};
#pragma unroll
        for (int nt = 0; nt < 4; ++nt) {
            const s16x8 b0 = *(const s16x8*)&QT[nt * 16 + c][q * 8];
            const s16x8 b1 = *(const s16x8*)&QT[nt * 16 + c][32 + q * 8];
#pragma unroll
            for (int mt = 0; mt < 4; ++mt) {
                u[mt][nt] = __builtin_amdgcn_mfma_f32_16x16x32_bf16(P[mt][0], b0,
                                                                    u[mt][nt], 0, 0, 0);
                u[mt][nt] = __builtin_amdgcn_mfma_f32_16x16x32_bf16(P[mt][1], b1,
                                                                    u[mt][nt], 0, 0, 0);
            }
        }
        BARRIER_RAW();  // dql/Sl/Ts visible; QT reads done -> PHT writes safe
        // exp (no stabilizer) -> PHT + np partials + free col-max tracking
#pragma unroll
        for (int nt = 0; nt < 4; ++nt) {
            const float dq = dql[nt * 16 + c];
            float np = 0.f;
            float vm = -3.4e38f;
#pragma unroll
            for (int mt = 0; mt < 4; ++mt) {
                vm = fmaxf(vm, fmaxf(fmaxf(u[mt][nt][0], u[mt][nt][1]),
                                     fmaxf(u[mt][nt][2], u[mt][nt][3])));
                const float e0 = __expf(__builtin_fmaf(u[mt][nt][0], DNRM, -dq));
                const float e1 = __expf(__builtin_fmaf(u[mt][nt][1], DNRM, -dq));
                const float e2 = __expf(__builtin_fmaf(u[mt][nt][2], DNRM, -dq));
                const float e3 = __expf(__builtin_fmaf(u[mt][nt][3], DNRM, -dq));
                const int mb = (4 * w + mt) * 16 + 4 * q;
                np += e0 * knr[mt][0] + e1 * knr[mt][1] + e2 * knr[mt][2] +
                      e3 * knr[mt][3];
                *(short4*)&PHT[nt * 16 + c][mb] = make_short4(
                    (short)f2b(e0), (short)f2b(e1), (short)f2b(e2), (short)f2b(e3));
            }
            np += __shfl_xor(np, 16, 64);
            np += __shfl_xor(np, 32, 64);
            vm = fmaxf(vm, __shfl_xor(vm, 16, 64));
            vm = fmaxf(vm, __shfl_xor(vm, 32, 64));
            if (q == 0) {
                npart[w][nt * 16 + c] = np;
                cw[w][nt * 16 + c] = vm;
            }
        }
        BARRIER_RAW();
        // PV GEMM: wave w owns n-tile w; B-frags pure LDS ds_read_b128
        f32x4 acc[4];
#pragma unroll
        for (int dt = 0; dt < 4; ++dt) acc[dt] = (f32x4){0.f, 0.f, 0.f, 0.f};
#pragma unroll
        for (int kc = 0; kc < 8; ++kc) {
            const s16x8 a = *(const s16x8*)&PHT[w * 16 + c][kc * 32 + q * 8];
#pragma unroll
            for (int dt = 0; dt < 4; ++dt) {
                const s16x8 b = *(const s16x8*)&KVL[dt * 16 + c][kc * 32 + q * 8];
                acc[dt] =
                    __builtin_amdgcn_mfma_f32_16x16x32_bf16(a, b, acc[dt], 0, 0, 0);
            }
        }
        BARRIER_RAW();  // PHT reads done; reuse as fp32 out tile [64][68]
        float* ot = (float*)&PHT[0][0];
        float rn[4], gm[4];
#pragma unroll
        for (int r = 0; r < 4; ++r) {
            const int nl = w * 16 + 4 * q + r;
            const float npsum = (npart[0][nl] + npart[1][nl]) +
                                (npart[2][nl] + npart[3][nl]);
            const float st =
                fmaxf(fmaxf(cw[0][nl], cw[1][nl]), fmaxf(cw[2][nl], cw[3][nl]));
            const float gamma = EPSV * __expf(st * DNRM);  // eps * e^{stab_n}
            gm[r] = gamma;
            rn[r] = 1.0f / (npsum + gamma * Tsh);
        }
#pragma unroll
        for (int dt = 0; dt < 4; ++dt)
#pragma unroll
            for (int r = 0; r < 4; ++r)
                ot[(dt * 16 + c) * 68 + (w * 16 + 4 * q + r)] =
                    (acc[dt][r] + gm[r] * Sl[dt * 16 + c]) * rn[r];
        BARRIER_RAW();  // ot visible
        {
            const int d = tid >> 2, ng = (tid & 3) * 16;
#pragma unroll
            for (int i = 0; i < 4; ++i) {
                const float4 v = *(const float4*)&ot[d * 68 + ng + i * 4];
                *(float4*)&op[d * Nv + n0 + t * 64 + ng + i * 4] = v;
            }
        }
        if (t == 0) {
            BARRIER_RAW();  // ot reads done -> QT/dred overwrite safe
            // stage Q tile1 from qqB (vmcnt wait auto-inserted here)
#pragma unroll
            for (int j = 0; j < 4; ++j) {
                const float v0 = ((const float*)&qqB[0])[j];
                const float v1 = ((const float*)&qqB[1])[j];
                const float v2 = ((const float*)&qqB[2])[j];
                const float v3 = ((const float*)&qqB[3])[j];
                *(short4*)&QT[4 * cs + j][4 * g] =
                    make_short4((short)f2b(v0), (short)f2b(v1), (short)f2b(v2),
                                (short)f2b(v3));
                dred[g][4 * cs + j] = (v0 * v0 + v1 * v1) + (v2 * v2 + v3 * v3);
            }
            BARRIER_RAW();  // tile1 staging visible
        }
    }
}

// ---------------------------------------------------------------------------
extern "C" void kernel_launch(void* const* d_in, const int* in_sizes, int n_in,
                              void* d_out, int out_size, void* d_ws, size_t ws_size,
                              hipStream_t stream) {
    const float* q = (const float*)d_in[0];
    const float* k = (const float*)d_in[1];
    const float* v = (const float*)d_in[2];
    const float* proj = (const float*)d_in[3];
    float* ws = (float*)d_ws;
    float* out = (float*)d_out;

    favor_kv<<<dim3(SPL, 32), 256, 0, stream>>>(k, v, proj, ws);
    favor_kvred<<<dim3(16, 32), 256, 0, stream>>>(ws);
    favor_out<<<dim3(Nv / 128, 32), 256, 0, stream>>>(q, proj, ws, out);
}